// Round 4
// baseline (326.107 us; speedup 1.0000x reference)
//
#include <hip/hip_runtime.h>
#include <stdint.h>

#define TDIM 512
#define FDIM 1024
#define NTOT 33554432.0f   // 64*512*1024
#define EPS  1e-5f

typedef unsigned short ushort_t;
typedef unsigned short ushort4_t __attribute__((ext_vector_type(4)));
typedef short short8 __attribute__((ext_vector_type(8)));
typedef float floatx4 __attribute__((ext_vector_type(4)));

__device__ __forceinline__ ushort_t f2bf(float f) {
    union { float f; uint32_t u; } v; v.f = f;
    uint32_t r = (v.u + 0x7fffu + ((v.u >> 16) & 1u)) >> 16;
    return (ushort_t)r;
}

// async global->LDS, 16B per lane; LDS dest is wave-uniform base + lane*16
__device__ __forceinline__ void async16(const void* g, void* l) {
    __builtin_amdgcn_global_load_lds(
        (const __attribute__((address_space(1))) void*)g,
        (__attribute__((address_space(3))) void*)l, 16, 0, 0);
}

// ---------------------------------------------------------------------------
// Kernel 1 (merged): blocks [0,4096): streaming sum/sumsq partials over x.
//                    blocks [4096,4608): W cast to chunked bf16 + row sums.
// xTC intermediary is GONE — k_gemm consumes raw x directly.
// ---------------------------------------------------------------------------
__global__ __launch_bounds__(256) void k_statsW(
    const float* __restrict__ x, const float* __restrict__ W,
    ushort_t* __restrict__ WbC, float* __restrict__ rowsumW,
    float2* __restrict__ partials)
{
    __shared__ float red[8];
    int tid = threadIdx.x, bid = blockIdx.x;
    int lane = tid & 63, w = tid >> 6;

    if (bid < 4096) {
        const float* xb = x + (size_t)bid * 8192;
        float s = 0.f, q = 0.f;
#pragma unroll
        for (int p = 0; p < 8; ++p) {
            float4 t = *(const float4*)(xb + p * 1024 + tid * 4);
            s += t.x + t.y + t.z + t.w;
            q += t.x * t.x + t.y * t.y + t.z * t.z + t.w * t.w;
        }
#pragma unroll
        for (int off = 32; off > 0; off >>= 1) {
            s += __shfl_down(s, off, 64);
            q += __shfl_down(q, off, 64);
        }
        if (lane == 0) { red[w] = s; red[4 + w] = q; }
        __syncthreads();
        if (tid == 0) {
            partials[bid] = make_float2(red[0] + red[1] + red[2] + red[3],
                                        red[4] + red[5] + red[6] + red[7]);
        }
    } else {
        int u = bid - 4096;
        float2 lv = *(const float2*)(W + (size_t)u * 512 + 2 * tid);

        int mt = u >> 7, m = u & 127;
        int kt = tid >> 4;
        int qq = (tid & 15) >> 2;
        int e  = 2 * (tid & 3);
        size_t off = ((size_t)(mt * 16 + kt)) * 4096 + (size_t)(qq * 128 + m) * 8 + e;
        uint32_t pk = (uint32_t)f2bf(lv.x) | ((uint32_t)f2bf(lv.y) << 16);
        *(uint32_t*)&WbC[off] = pk;

        float s = lv.x + lv.y;
#pragma unroll
        for (int off2 = 32; off2 > 0; off2 >>= 1) s += __shfl_down(s, off2, 64);
        if (lane == 0) red[w] = s;
        __syncthreads();
        if (tid == 0) rowsumW[u] = red[0] + red[1] + red[2] + red[3];
    }
}

// ---------------------------------------------------------------------------
// Kernel 2: single-block final reduce: partials -> a; d[u] = c*rowsumW + bias.
// ---------------------------------------------------------------------------
__global__ __launch_bounds__(256) void k_reduce(
    const float2* __restrict__ partials, const float* __restrict__ rowsumW,
    const float* __restrict__ bias, const float* __restrict__ gamma,
    const float* __restrict__ beta, float* __restrict__ stats,
    float* __restrict__ d)
{
    __shared__ float red[8];
    __shared__ float sac[2];
    int tid = threadIdx.x;
    float s = 0.f, q = 0.f;
#pragma unroll
    for (int i = 0; i < 16; ++i) {
        float2 p = partials[i * 256 + tid];
        s += p.x; q += p.y;
    }
#pragma unroll
    for (int off = 32; off > 0; off >>= 1) {
        s += __shfl_down(s, off, 64);
        q += __shfl_down(q, off, 64);
    }
    int lane = tid & 63, w = tid >> 6;
    if (lane == 0) { red[w] = s; red[4 + w] = q; }
    __syncthreads();
    if (tid == 0) {
        float S = red[0] + red[1] + red[2] + red[3];
        float Q = red[4] + red[5] + red[6] + red[7];
        float mean = S * (1.f / NTOT);
        float var  = Q * (1.f / NTOT) - mean * mean;
        float a    = gamma[0] * rsqrtf(var + EPS);
        float c    = beta[0] - mean * a;
        stats[0] = a;
        sac[0] = a; sac[1] = c;
    }
    __syncthreads();
    float c = sac[1];
    d[tid]       = c * rowsumW[tid]       + bias[tid];
    d[tid + 256] = c * rowsumW[tid + 256] + bias[tid + 256];
}

// ---------------------------------------------------------------------------
// Kernel 3: GEMM v5 — fused transpose: B staged as RAW f32 x-tile via
// global_load_lds with XOR-pre-swizzled SOURCE (rule #21: linear LDS dest,
// inverse-swizzled global src, swizzled read).
//   LDS slot = A 8KB (chunked bf16, as before) + B 16KB (f32 [32t][128f],
//   word index t*128 + (f ^ ((t>>3)<<3))). 2 slots = 48KB, counted vmcnt(6).
//   B-frag: 8x ds_read_b32 stride-128 (2-way across wave = free) + RNE f2bf
//   in-register (identical numerics to the old xTC path).
//   XCD-bijective grid swizzle kept (4 mt-blocks sharing an x panel -> same
//   XCD, consecutive slots -> L2-served reuse; x is L3-resident after stats).
// ---------------------------------------------------------------------------
__global__ __launch_bounds__(256) void k_gemm(
    const ushort_t* __restrict__ WbC, const float* __restrict__ x,
    const float* __restrict__ d, const float* __restrict__ stats,
    float* __restrict__ out)
{
    __shared__ ulong smem_raw[6144];             // 49152 B: 2 x (A 8K + B 16K)
    char*  lds  = (char*)smem_raw;
    float* ldsC = (float*)smem_raw;              // 32*132*4 = 16896 B (epilogue)

    int tid = threadIdx.x;
    int w = tid >> 6, lane = tid & 63;

    // XCD-bijective decode: hb = xcd + 8*(mt + 4*slot); nt = slot*8 + xcd
    int hb   = blockIdx.x;               // 0..2047
    int xcd  = hb & 7;
    int rr   = hb >> 3;                  // 0..255
    int mt   = rr & 3;                   // 0..3   (u tile)
    int nt   = ((rr >> 2) << 3) + xcd;   // 0..511 (b, f tile)
    int b = nt >> 3, ft = nt & 7;

    int wr = w >> 1, wc = w & 1;
    int l15 = lane & 15, q = lane >> 4;

    const ushort_t* Ab = WbC + (size_t)mt * 16 * 4096 + tid * 8;

    // B stage sources: chunk c covers t_loc = (tid>>5)+c*8, 4 floats at
    // fx = (tid&31)*4; stored value must be x[t][fx ^ ((t>>3)<<3)] so that
    // the LDS image is the swizzled layout while gload_lds writes linearly.
    const float* Bs[4];
    {
        int tl0 = tid >> 5, fx = (tid & 31) * 4;
#pragma unroll
        for (int c = 0; c < 4; ++c) {
            int tl = tl0 + c * 8;
            int f  = fx ^ (((tl >> 3) & 3) << 3);
            Bs[c] = x + ((size_t)b * TDIM + tl) * FDIM + ft * 128 + f;
        }
    }

    floatx4 acc[4][4] = {};

    auto stage = [&](int kt, int s) {
        char* ls = lds + s * 24576;
        const ushort_t* Ag = Ab + kt * 4096;
        async16(Ag,        ls + tid * 16);
        async16(Ag + 2048, ls + 4096 + tid * 16);
        char* lb = ls + 8192;
        size_t koff = (size_t)kt * 32 * FDIM;
#pragma unroll
        for (int c = 0; c < 4; ++c)
            async16(Bs[c] + koff, lb + c * 4096 + tid * 16);
    };

    // prologue: depth-1 prefetch
    stage(0, 0);

#pragma unroll
    for (int kt = 0; kt < 16; ++kt) {
        if (kt < 15) {
            stage(kt + 1, (kt + 1) & 1);
            asm volatile("s_waitcnt vmcnt(6)" ::: "memory");   // stage(kt) done
        } else {
            asm volatile("s_waitcnt vmcnt(0)" ::: "memory");
        }
        __builtin_amdgcn_s_barrier();        // slot kt ready for ALL waves

        char* ls = lds + (kt & 1) * 24576;
        const ushort_t* cA = (const ushort_t*)ls;
        const float*    cB = (const float*)(ls + 8192);

        short8 af[4], bfr[4];
#pragma unroll
        for (int i = 0; i < 4; ++i) {
            int m = wr * 64 + i * 16 + l15;
            af[i] = *(const short8*)&cA[(q * 128 + m) * 8];
        }
#pragma unroll
        for (int j = 0; j < 4; ++j) {
            int fxr = (wc * 64 + j * 16 + l15) ^ (q << 3);
            float xv[8];
#pragma unroll
            for (int e = 0; e < 8; ++e)
                xv[e] = cB[(q * 8 + e) * 128 + fxr];
            short8 bv;
#pragma unroll
            for (int e = 0; e < 8; ++e) bv[e] = (short)f2bf(xv[e]);
            bfr[j] = bv;
        }
        // reads must complete before next iter's stage overwrites the slot
        asm volatile("s_waitcnt lgkmcnt(0)" ::: "memory");
        __builtin_amdgcn_s_barrier();

#pragma unroll
        for (int i = 0; i < 4; ++i)
#pragma unroll
            for (int j = 0; j < 4; ++j)
                acc[i][j] = __builtin_amdgcn_mfma_f32_16x16x32_bf16(
                    af[i], bfr[j], acc[i][j], 0, 0, 0);
    }

    __syncthreads();   // full drain before ldsC aliases the ring

    // epilogue: 4 passes of 32 rows through LDS (stride 132 -> 2-way only).
    // residual x rows are a subset of the panel just read -> L2-hot.
    float a = stats[0];
    int row = tid >> 3, cs = (tid & 7) * 16;
#pragma unroll
    for (int p = 0; p < 4; ++p) {
        if (wr == (p >> 1)) {
#pragma unroll
            for (int ii = 0; ii < 2; ++ii) {
                int i = (p & 1) * 2 + ii;
                int rl0 = i * 16 + q * 4 - (p & 1) * 32;
#pragma unroll
                for (int j = 0; j < 4; ++j) {
                    int col = wc * 64 + j * 16 + l15;
#pragma unroll
                    for (int r = 0; r < 4; ++r)
                        ldsC[(rl0 + r) * 132 + col] = acc[i][j][r];
                }
            }
        }
        __syncthreads();
        int tg = mt * 128 + p * 32 + row;
        float dt = d[tg];
        size_t gbase = ((size_t)b * TDIM + tg) * FDIM + ft * 128 + cs;
        const float* xr = x + gbase;
        float* orow = out + gbase;
#pragma unroll
        for (int k4 = 0; k4 < 4; ++k4) {
            float4 xv = *(const float4*)(xr + k4 * 4);
            float4 cv = *(const float4*)&ldsC[row * 132 + cs + k4 * 4];
            float4 o;
            o.x = xv.x + fmaxf(a * cv.x + dt, 0.f);
            o.y = xv.y + fmaxf(a * cv.y + dt, 0.f);
            o.z = xv.z + fmaxf(a * cv.z + dt, 0.f);
            o.w = xv.w + fmaxf(a * cv.w + dt, 0.f);
            *(float4*)(orow + k4 * 4) = o;
        }
        __syncthreads();
    }
}

// ---------------------------------------------------------------------------
extern "C" void kernel_launch(void* const* d_in, const int* in_sizes, int n_in,
                              void* d_out, int out_size, void* d_ws, size_t ws_size,
                              hipStream_t stream) {
    const float* x     = (const float*)d_in[0];
    const float* W     = (const float*)d_in[1];
    const float* bias  = (const float*)d_in[2];
    const float* gamma = (const float*)d_in[3];
    const float* beta  = (const float*)d_in[4];
    float* out = (float*)d_out;

    char* ws = (char*)d_ws;
    float*    stats    = (float*)ws;                   // 8 B
    float*    dvec     = (float*)(ws + 1024);          // 2 KB
    float*    rowsumW  = (float*)(ws + 4096);          // 2 KB
    float2*   partials = (float2*)(ws + 8192);         // 32 KB
    ushort_t* WbC      = (ushort_t*)(ws + (64 << 10)); // 512 KB; total < 1 MB

    k_statsW<<<4608, 256, 0, stream>>>(x, W, WbC, rowsumW, partials);
    k_reduce<<<1, 256, 0, stream>>>(partials, rowsumW, bias, gamma, beta, stats, dvec);
    k_gemm<<<2048, 256, 0, stream>>>(WbC, x, dvec, stats, out);
}

// Round 5
// 316.430 us; speedup vs baseline: 1.0306x; 1.0306x over previous
//
#include <hip/hip_runtime.h>
#include <stdint.h>

#define TDIM 512
#define FDIM 1024
#define NTOT 33554432.0f   // 64*512*1024
#define EPS  1e-5f

typedef unsigned short ushort_t;
typedef unsigned short ushort4_t __attribute__((ext_vector_type(4)));
typedef short short8 __attribute__((ext_vector_type(8)));
typedef float floatx4 __attribute__((ext_vector_type(4)));

__device__ __forceinline__ ushort_t f2bf(float f) {
    union { float f; uint32_t u; } v; v.f = f;
    uint32_t r = (v.u + 0x7fffu + ((v.u >> 16) & 1u)) >> 16;
    return (ushort_t)r;
}

// async global->LDS, 16B per lane; LDS dest is wave-uniform base + lane*16
__device__ __forceinline__ void async16(const ushort_t* g, ushort_t* l) {
    __builtin_amdgcn_global_load_lds(
        (const __attribute__((address_space(1))) void*)g,
        (__attribute__((address_space(3))) void*)l, 16, 0, 0);
}

// Chunked tile layout (the GEMM's exact LDS image, 8KB per (tile, kt)):
//   tile(b,ft,kt) base = ((b*8+ft)*16 + kt) * 4096 ushorts
//   element (k,n): offset (q*128 + n)*8 + e,  q=(k&31)>>3, e=k&7, n=col&127

// ---------------------------------------------------------------------------
// Kernel 1 (merged): blocks [0,4096): stats partials + xT chunked-bf16 write
//                    blocks [4096,4608): W cast to chunked bf16 + row sums
// ---------------------------------------------------------------------------
__global__ __launch_bounds__(256) void k_statsT(
    const float* __restrict__ x, const float* __restrict__ W,
    ushort_t* __restrict__ xTC, ushort_t* __restrict__ WbC,
    float* __restrict__ rowsumW, float2* __restrict__ partials)
{
    __shared__ ushort_t tile[64 * 128];   // [t][f], 16KB
    __shared__ float red[8];

    int tid = threadIdx.x, bid = blockIdx.x;
    int lane = tid & 63, w = tid >> 6;

    if (bid >= 4096) {
        // ---- W-cast branch (512 blocks) ----
        int u = bid - 4096;
        float2 lv = *(const float2*)(W + (size_t)u * 512 + 2 * tid);

        int mt = u >> 7, m = u & 127;
        int kt = tid >> 4;
        int qq = (tid & 15) >> 2;
        int e  = 2 * (tid & 3);
        size_t off = ((size_t)(mt * 16 + kt)) * 4096 + (size_t)(qq * 128 + m) * 8 + e;
        uint32_t pk = (uint32_t)f2bf(lv.x) | ((uint32_t)f2bf(lv.y) << 16);
        *(uint32_t*)&WbC[off] = pk;

        float s = lv.x + lv.y;
#pragma unroll
        for (int off2 = 32; off2 > 0; off2 >>= 1) s += __shfl_down(s, off2, 64);
        if (lane == 0) red[w] = s;
        __syncthreads();
        if (tid == 0) rowsumW[u] = red[0] + red[1] + red[2] + red[3];
        return;
    }

    // ---- stats + transpose branch (4096 blocks) ----
    int b  = bid >> 6;
    int t0 = ((bid >> 3) & 7) << 6;
    int ft = bid & 7;
    int f0 = ft << 7;

    int r8 = tid >> 5, c8 = tid & 31;
    const float* xb = x + ((size_t)(b * TDIM + t0) * FDIM) + f0;

    float4 v[8];
#pragma unroll
    for (int p = 0; p < 8; ++p)
        v[p] = *(const float4*)(xb + (size_t)(p * 8 + r8) * FDIM + c8 * 4);

    float s = 0.f, q = 0.f;
#pragma unroll
    for (int p = 0; p < 8; ++p) {
        float4 t = v[p];
        s += t.x + t.y + t.z + t.w;
        q += t.x * t.x + t.y * t.y + t.z * t.z + t.w * t.w;
        ushort4_t pk;
        pk[0] = f2bf(t.x); pk[1] = f2bf(t.y); pk[2] = f2bf(t.z); pk[3] = f2bf(t.w);
        *(ushort4_t*)&tile[(p * 8 + r8) * 128 + c8 * 4] = pk;   // b64, conflict-free
    }

#pragma unroll
    for (int off = 32; off > 0; off >>= 1) {
        s += __shfl_down(s, off, 64);
        q += __shfl_down(q, off, 64);
    }
    if (lane == 0) { red[w] = s; red[4 + w] = q; }
    __syncthreads();   // covers tile writes AND red[]
    if (tid == 0) {
        partials[bid] = make_float2(red[0] + red[1] + red[2] + red[3],
                                    red[4] + red[5] + red[6] + red[7]);
    }

    // phase 2: gather-transpose to chunked layout; stores are lane-contiguous
    // 16B -> 1KB/wave coalesced. LDS u16 gathers are 2-way (free).
    int fl = tid & 127, hf = tid >> 7;
    size_t base = ((size_t)((b * 8 + ft) * 16) + (t0 >> 5) + hf) * 4096;
#pragma unroll
    for (int qq = 0; qq < 4; ++qq) {
        int tr = hf * 32 + qq * 8;
        uint32_t w0 = (uint32_t)tile[(tr + 0) * 128 + fl] | ((uint32_t)tile[(tr + 1) * 128 + fl] << 16);
        uint32_t w1 = (uint32_t)tile[(tr + 2) * 128 + fl] | ((uint32_t)tile[(tr + 3) * 128 + fl] << 16);
        uint32_t w2 = (uint32_t)tile[(tr + 4) * 128 + fl] | ((uint32_t)tile[(tr + 5) * 128 + fl] << 16);
        uint32_t w3 = (uint32_t)tile[(tr + 6) * 128 + fl] | ((uint32_t)tile[(tr + 7) * 128 + fl] << 16);
        uint4 o = make_uint4(w0, w1, w2, w3);
        *(uint4*)&xTC[base + (size_t)(qq * 128 + fl) * 8] = o;
    }
}

// ---------------------------------------------------------------------------
// Kernel 2: single-block final reduce: partials -> a; d[u] = c*rowsumW + bias.
// ---------------------------------------------------------------------------
__global__ __launch_bounds__(256) void k_reduce(
    const float2* __restrict__ partials, const float* __restrict__ rowsumW,
    const float* __restrict__ bias, const float* __restrict__ gamma,
    const float* __restrict__ beta, float* __restrict__ stats,
    float* __restrict__ d)
{
    __shared__ float red[8];
    __shared__ float sac[2];
    int tid = threadIdx.x;
    float s = 0.f, q = 0.f;
#pragma unroll
    for (int i = 0; i < 16; ++i) {
        float2 p = partials[i * 256 + tid];
        s += p.x; q += p.y;
    }
#pragma unroll
    for (int off = 32; off > 0; off >>= 1) {
        s += __shfl_down(s, off, 64);
        q += __shfl_down(q, off, 64);
    }
    int lane = tid & 63, w = tid >> 6;
    if (lane == 0) { red[w] = s; red[4 + w] = q; }
    __syncthreads();
    if (tid == 0) {
        float S = red[0] + red[1] + red[2] + red[3];
        float Q = red[4] + red[5] + red[6] + red[7];
        float mean = S * (1.f / NTOT);
        float var  = Q * (1.f / NTOT) - mean * mean;
        float a    = gamma[0] * rsqrtf(var + EPS);
        float c    = beta[0] - mean * a;
        stats[0] = a;
        sac[0] = a; sac[1] = c;
    }
    __syncthreads();
    float c = sac[1];
    d[tid]       = c * rowsumW[tid]       + bias[tid];
    d[tid + 256] = c * rowsumW[tid + 256] + bias[tid + 256];
}

// ---------------------------------------------------------------------------
// Kernel 3: GEMM v6 = v4 core (best measured, 91us) with occupancy fix:
//   * 2-slot LDS ring (32KB, was 3x16KB=48KB): LDS cap 3 -> 5 blocks/CU.
//     Counted vmcnt(4): stage(kt+1) issued, wait only for stage(kt) —
//     still a full compute-iteration of latency tolerance per stage.
//   * T5: s_setprio(1) around the MFMA cluster (counted-vmcnt phases give
//     waves role diversity; m224: setprio pays on such structures).
//   * XCD-bijective grid swizzle kept (FETCH 199 -> 106 MB, proven).
// ---------------------------------------------------------------------------
__global__ __launch_bounds__(256) void k_gemm(
    const ushort_t* __restrict__ WbC, const ushort_t* __restrict__ xTC,
    const float* __restrict__ x, const float* __restrict__ d,
    const float* __restrict__ stats, float* __restrict__ out)
{
    __shared__ ulong smem_raw[4096];             // 32768 B: 2 slots x (A8K+B8K)
    ushort_t* lds  = (ushort_t*)smem_raw;
    float*    ldsC = (float*)smem_raw;           // 32*132*4 = 16896 B (epilogue)

    int tid = threadIdx.x;
    int w = tid >> 6, lane = tid & 63;

    // XCD-bijective decode: hb = xcd + 8*(mt + 4*slot); nt = slot*8 + xcd
    int hb   = blockIdx.x;               // 0..2047
    int xcd  = hb & 7;
    int rr   = hb >> 3;                  // 0..255
    int mt   = rr & 3;                   // 0..3   (u tile)
    int nt   = ((rr >> 2) << 3) + xcd;   // 0..511 (b, f tile)
    int b = nt >> 3, ft = nt & 7;

    int wr = w >> 1, wc = w & 1;
    int l15 = lane & 15, q = lane >> 4;

    const ushort_t* Ab = WbC + (size_t)mt * 16 * 4096 + tid * 8;
    const ushort_t* Bb = xTC + (size_t)(b * 8 + ft) * 16 * 4096 + tid * 8;

    floatx4 acc[4][4] = {};

    // stage K-tile kt into ring slot s (4 x 16B gload_lds per thread)
    auto stage = [&](int kt, int s) {
        const ushort_t* Ag = Ab + kt * 4096;
        const ushort_t* Bg = Bb + kt * 4096;
        ushort_t* ls = lds + s * 8192;
        async16(Ag,        &ls[tid * 8]);
        async16(Ag + 2048, &ls[2048 + tid * 8]);
        async16(Bg,        &ls[4096 + tid * 8]);
        async16(Bg + 2048, &ls[4096 + 2048 + tid * 8]);
    };

    // prologue: depth-1 prefetch
    stage(0, 0);

#pragma unroll
    for (int kt = 0; kt < 16; ++kt) {
        if (kt < 15) {
            stage(kt + 1, (kt + 1) & 1);
            asm volatile("s_waitcnt vmcnt(4)" ::: "memory");   // stage(kt) done
        } else {
            asm volatile("s_waitcnt vmcnt(0)" ::: "memory");   // stage(15) done
        }
        __builtin_amdgcn_s_barrier();        // slot kt ready for ALL waves

        const ushort_t* cA = lds + (kt & 1) * 8192;
        const ushort_t* cB = cA + 4096;
        short8 af[4], bfr[4];
#pragma unroll
        for (int i = 0; i < 4; ++i) {
            int m = wr * 64 + i * 16 + l15;
            af[i] = *(const short8*)&cA[(q * 128 + m) * 8];
        }
#pragma unroll
        for (int j = 0; j < 4; ++j) {
            int n = wc * 64 + j * 16 + l15;
            bfr[j] = *(const short8*)&cB[(q * 128 + n) * 8];
        }
        // reads must complete before any wave's next-iter stage overwrites slot
        asm volatile("s_waitcnt lgkmcnt(0)" ::: "memory");
        __builtin_amdgcn_s_barrier();

        __builtin_amdgcn_s_setprio(1);
#pragma unroll
        for (int i = 0; i < 4; ++i)
#pragma unroll
            for (int j = 0; j < 4; ++j)
                acc[i][j] = __builtin_amdgcn_mfma_f32_16x16x32_bf16(
                    af[i], bfr[j], acc[i][j], 0, 0, 0);
        __builtin_amdgcn_s_setprio(0);
    }

    __syncthreads();   // full drain before ldsC aliases the ring

    // epilogue: 4 passes of 32 rows through LDS (stride 132 -> 2-way only)
    float a = stats[0];
    int row = tid >> 3, cs = (tid & 7) * 16;
#pragma unroll
    for (int p = 0; p < 4; ++p) {
        if (wr == (p >> 1)) {
#pragma unroll
            for (int ii = 0; ii < 2; ++ii) {
                int i = (p & 1) * 2 + ii;
                int rl0 = i * 16 + q * 4 - (p & 1) * 32;
#pragma unroll
                for (int j = 0; j < 4; ++j) {
                    int col = wc * 64 + j * 16 + l15;
#pragma unroll
                    for (int r = 0; r < 4; ++r)
                        ldsC[(rl0 + r) * 132 + col] = acc[i][j][r];
                }
            }
        }
        __syncthreads();
        int tg = mt * 128 + p * 32 + row;
        float dt = d[tg];
        size_t gbase = ((size_t)b * TDIM + tg) * FDIM + ft * 128 + cs;
        const float* xr = x + gbase;
        float* orow = out + gbase;
#pragma unroll
        for (int k4 = 0; k4 < 4; ++k4) {
            float4 xv = *(const float4*)(xr + k4 * 4);
            float4 cv = *(const float4*)&ldsC[row * 132 + cs + k4 * 4];
            float4 o;
            o.x = xv.x + fmaxf(a * cv.x + dt, 0.f);
            o.y = xv.y + fmaxf(a * cv.y + dt, 0.f);
            o.z = xv.z + fmaxf(a * cv.z + dt, 0.f);
            o.w = xv.w + fmaxf(a * cv.w + dt, 0.f);
            *(float4*)(orow + k4 * 4) = o;
        }
        __syncthreads();
    }
}

// ---------------------------------------------------------------------------
extern "C" void kernel_launch(void* const* d_in, const int* in_sizes, int n_in,
                              void* d_out, int out_size, void* d_ws, size_t ws_size,
                              hipStream_t stream) {
    const float* x     = (const float*)d_in[0];
    const float* W     = (const float*)d_in[1];
    const float* bias  = (const float*)d_in[2];
    const float* gamma = (const float*)d_in[3];
    const float* beta  = (const float*)d_in[4];
    float* out = (float*)d_out;

    char* ws = (char*)d_ws;
    float*    stats    = (float*)ws;                   // 8 B
    float*    dvec     = (float*)(ws + 1024);          // 2 KB
    float*    rowsumW  = (float*)(ws + 4096);          // 2 KB
    float2*   partials = (float2*)(ws + 8192);         // 32 KB
    ushort_t* WbC      = (ushort_t*)(ws + (64 << 10)); // 512 KB
    ushort_t* xTC      = (ushort_t*)(ws + (1 << 20));  // 64 MB

    k_statsT<<<4608, 256, 0, stream>>>(x, W, xTC, WbC, rowsumW, partials);
    k_reduce<<<1, 256, 0, stream>>>(partials, rowsumW, bias, gamma, beta, stats, dvec);
    k_gemm<<<2048, 256, 0, stream>>>(WbC, xTC, x, dvec, stats, out);
}

// Round 6
// 310.510 us; speedup vs baseline: 1.0502x; 1.0191x over previous
//
#include <hip/hip_runtime.h>
#include <stdint.h>

#define TDIM 512
#define FDIM 1024
#define NTOT 33554432.0f   // 64*512*1024
#define EPS  1e-5f

typedef unsigned short ushort_t;
typedef unsigned short ushort4_t __attribute__((ext_vector_type(4)));
typedef short short8 __attribute__((ext_vector_type(8)));
typedef float floatx4 __attribute__((ext_vector_type(4)));

__device__ __forceinline__ ushort_t f2bf(float f) {
    union { float f; uint32_t u; } v; v.f = f;
    uint32_t r = (v.u + 0x7fffu + ((v.u >> 16) & 1u)) >> 16;
    return (ushort_t)r;
}

// async global->LDS, 16B per lane; LDS dest is wave-uniform base + lane*16
__device__ __forceinline__ void async16(const ushort_t* g, ushort_t* l) {
    __builtin_amdgcn_global_load_lds(
        (const __attribute__((address_space(1))) void*)g,
        (__attribute__((address_space(3))) void*)l, 16, 0, 0);
}

// Chunked tile layout (the GEMM's exact LDS image, 8KB per (tile, kt)):
//   tile(b,ft,kt) base = ((b*8+ft)*16 + kt) * 4096 ushorts
//   element (k,n): offset (q*128 + n)*8 + e,  q=(k&31)>>3, e=k&7, n=col&127

// ---------------------------------------------------------------------------
// Kernel 1 (merged): blocks [0,4096): stats partials + xT chunked-bf16 write
//                    blocks [4096,4608): W cast to chunked bf16 + row sums
// ---------------------------------------------------------------------------
__global__ __launch_bounds__(256) void k_statsT(
    const float* __restrict__ x, const float* __restrict__ W,
    ushort_t* __restrict__ xTC, ushort_t* __restrict__ WbC,
    float* __restrict__ rowsumW, float2* __restrict__ partials)
{
    __shared__ ushort_t tile[64 * 128];   // [t][f], 16KB
    __shared__ float red[8];

    int tid = threadIdx.x, bid = blockIdx.x;
    int lane = tid & 63, w = tid >> 6;

    if (bid >= 4096) {
        // ---- W-cast branch (512 blocks) ----
        int u = bid - 4096;
        float2 lv = *(const float2*)(W + (size_t)u * 512 + 2 * tid);

        int mt = u >> 7, m = u & 127;
        int kt = tid >> 4;
        int qq = (tid & 15) >> 2;
        int e  = 2 * (tid & 3);
        size_t off = ((size_t)(mt * 16 + kt)) * 4096 + (size_t)(qq * 128 + m) * 8 + e;
        uint32_t pk = (uint32_t)f2bf(lv.x) | ((uint32_t)f2bf(lv.y) << 16);
        *(uint32_t*)&WbC[off] = pk;

        float s = lv.x + lv.y;
#pragma unroll
        for (int off2 = 32; off2 > 0; off2 >>= 1) s += __shfl_down(s, off2, 64);
        if (lane == 0) red[w] = s;
        __syncthreads();
        if (tid == 0) rowsumW[u] = red[0] + red[1] + red[2] + red[3];
        return;
    }

    // ---- stats + transpose branch (4096 blocks) ----
    int b  = bid >> 6;
    int t0 = ((bid >> 3) & 7) << 6;
    int ft = bid & 7;
    int f0 = ft << 7;

    int r8 = tid >> 5, c8 = tid & 31;
    const float* xb = x + ((size_t)(b * TDIM + t0) * FDIM) + f0;

    float4 v[8];
#pragma unroll
    for (int p = 0; p < 8; ++p)
        v[p] = *(const float4*)(xb + (size_t)(p * 8 + r8) * FDIM + c8 * 4);

    float s = 0.f, q = 0.f;
#pragma unroll
    for (int p = 0; p < 8; ++p) {
        float4 t = v[p];
        s += t.x + t.y + t.z + t.w;
        q += t.x * t.x + t.y * t.y + t.z * t.z + t.w * t.w;
        ushort4_t pk;
        pk[0] = f2bf(t.x); pk[1] = f2bf(t.y); pk[2] = f2bf(t.z); pk[3] = f2bf(t.w);
        *(ushort4_t*)&tile[(p * 8 + r8) * 128 + c8 * 4] = pk;   // b64, conflict-free
    }

#pragma unroll
    for (int off = 32; off > 0; off >>= 1) {
        s += __shfl_down(s, off, 64);
        q += __shfl_down(q, off, 64);
    }
    if (lane == 0) { red[w] = s; red[4 + w] = q; }
    __syncthreads();   // covers tile writes AND red[]
    if (tid == 0) {
        partials[bid] = make_float2(red[0] + red[1] + red[2] + red[3],
                                    red[4] + red[5] + red[6] + red[7]);
    }

    // phase 2: gather-transpose to chunked layout; stores are lane-contiguous
    // 16B -> 1KB/wave coalesced. LDS u16 gathers are 2-way (free).
    int fl = tid & 127, hf = tid >> 7;
    size_t base = ((size_t)((b * 8 + ft) * 16) + (t0 >> 5) + hf) * 4096;
#pragma unroll
    for (int qq = 0; qq < 4; ++qq) {
        int tr = hf * 32 + qq * 8;
        uint32_t w0 = (uint32_t)tile[(tr + 0) * 128 + fl] | ((uint32_t)tile[(tr + 1) * 128 + fl] << 16);
        uint32_t w1 = (uint32_t)tile[(tr + 2) * 128 + fl] | ((uint32_t)tile[(tr + 3) * 128 + fl] << 16);
        uint32_t w2 = (uint32_t)tile[(tr + 4) * 128 + fl] | ((uint32_t)tile[(tr + 5) * 128 + fl] << 16);
        uint32_t w3 = (uint32_t)tile[(tr + 6) * 128 + fl] | ((uint32_t)tile[(tr + 7) * 128 + fl] << 16);
        uint4 o = make_uint4(w0, w1, w2, w3);
        *(uint4*)&xTC[base + (size_t)(qq * 128 + fl) * 8] = o;
    }
}

// ---------------------------------------------------------------------------
// Kernel 2: single-block final reduce: partials -> a; d[u] = c*rowsumW + bias.
// ---------------------------------------------------------------------------
__global__ __launch_bounds__(256) void k_reduce(
    const float2* __restrict__ partials, const float* __restrict__ rowsumW,
    const float* __restrict__ bias, const float* __restrict__ gamma,
    const float* __restrict__ beta, float* __restrict__ stats,
    float* __restrict__ d)
{
    __shared__ float red[8];
    __shared__ float sac[2];
    int tid = threadIdx.x;
    float s = 0.f, q = 0.f;
#pragma unroll
    for (int i = 0; i < 16; ++i) {
        float2 p = partials[i * 256 + tid];
        s += p.x; q += p.y;
    }
#pragma unroll
    for (int off = 32; off > 0; off >>= 1) {
        s += __shfl_down(s, off, 64);
        q += __shfl_down(q, off, 64);
    }
    int lane = tid & 63, w = tid >> 6;
    if (lane == 0) { red[w] = s; red[4 + w] = q; }
    __syncthreads();
    if (tid == 0) {
        float S = red[0] + red[1] + red[2] + red[3];
        float Q = red[4] + red[5] + red[6] + red[7];
        float mean = S * (1.f / NTOT);
        float var  = Q * (1.f / NTOT) - mean * mean;
        float a    = gamma[0] * rsqrtf(var + EPS);
        float c    = beta[0] - mean * a;
        stats[0] = a;
        sac[0] = a; sac[1] = c;
    }
    __syncthreads();
    float c = sac[1];
    d[tid]       = c * rowsumW[tid]       + bias[tid];
    d[tid + 256] = c * rowsumW[tid + 256] + bias[tid + 256];
}

// ---------------------------------------------------------------------------
// Kernel 3: GEMM v7 = v4 core (3-slot ring, vmcnt(8), depth-2 prefetch —
// best measured 91us) + FRAGMENT SOFTWARE PIPELINE:
//   double register frag set; at iter kt: issue ds_reads for frags(kt),
//   then run MFMA of frags(kt-1) (reg-only, independent — hides ds_read
//   latency), then lgkmcnt(0)+barrier (WAR guard before stage(kt+3)
//   overwrites the slot). Tail MFMA(15) after the loop.
// ---------------------------------------------------------------------------
__global__ __launch_bounds__(256) void k_gemm(
    const ushort_t* __restrict__ WbC, const ushort_t* __restrict__ xTC,
    const float* __restrict__ x, const float* __restrict__ d,
    const float* __restrict__ stats, float* __restrict__ out)
{
    __shared__ ulong smem_raw[6144];             // 49152 B: 3 slots x (A8K+B8K)
    ushort_t* lds  = (ushort_t*)smem_raw;
    float*    ldsC = (float*)smem_raw;           // 32*132*4 = 16896 B (epilogue)

    int tid = threadIdx.x;
    int w = tid >> 6, lane = tid & 63;

    // XCD-bijective decode: hb = xcd + 8*(mt + 4*slot); nt = slot*8 + xcd
    int hb   = blockIdx.x;               // 0..2047
    int xcd  = hb & 7;
    int rr   = hb >> 3;                  // 0..255
    int mt   = rr & 3;                   // 0..3   (u tile)
    int nt   = ((rr >> 2) << 3) + xcd;   // 0..511 (b, f tile)
    int b = nt >> 3, ft = nt & 7;

    int wr = w >> 1, wc = w & 1;
    int l15 = lane & 15, q = lane >> 4;

    const ushort_t* Ab = WbC + (size_t)mt * 16 * 4096 + tid * 8;
    const ushort_t* Bb = xTC + (size_t)(b * 8 + ft) * 16 * 4096 + tid * 8;

    floatx4 acc[4][4] = {};

    // stage K-tile kt into ring slot s (4 x 16B gload_lds per thread)
    auto stage = [&](int kt, int s) {
        const ushort_t* Ag = Ab + kt * 4096;
        const ushort_t* Bg = Bb + kt * 4096;
        ushort_t* ls = lds + s * 8192;
        async16(Ag,        &ls[tid * 8]);
        async16(Ag + 2048, &ls[2048 + tid * 8]);
        async16(Bg,        &ls[4096 + tid * 8]);
        async16(Bg + 2048, &ls[4096 + 2048 + tid * 8]);
    };

    // prologue: 2-deep prefetch
    stage(0, 0);
    stage(1, 1);

    short8 af[2][4], bfr[2][4];          // double frag set (static-indexed)

#pragma unroll
    for (int kt = 0; kt < 16; ++kt) {
        if (kt < 14) {
            stage(kt + 2, (kt + 2) % 3);
            asm volatile("s_waitcnt vmcnt(8)" ::: "memory");   // stage(kt) done
        } else if (kt == 14) {
            asm volatile("s_waitcnt vmcnt(4)" ::: "memory");   // stage(14) done
        } else {
            asm volatile("s_waitcnt vmcnt(0)" ::: "memory");   // stage(15) done
        }
        __builtin_amdgcn_s_barrier();        // slot kt ready for ALL waves

        const ushort_t* cA = lds + (kt % 3) * 8192;
        const ushort_t* cB = cA + 4096;
        const int cs = kt & 1, ps = cs ^ 1;  // compile-time in unrolled body

        // issue this tile's fragment reads (latency hidden by MFMA below)
#pragma unroll
        for (int i = 0; i < 4; ++i) {
            int m = wr * 64 + i * 16 + l15;
            af[cs][i] = *(const short8*)&cA[(q * 128 + m) * 8];
        }
#pragma unroll
        for (int j = 0; j < 4; ++j) {
            int n = wc * 64 + j * 16 + l15;
            bfr[cs][j] = *(const short8*)&cB[(q * 128 + n) * 8];
        }

        // MFMA on the PREVIOUS tile's fragments (register-only, independent)
        if (kt > 0) {
#pragma unroll
            for (int i = 0; i < 4; ++i)
#pragma unroll
                for (int j = 0; j < 4; ++j)
                    acc[i][j] = __builtin_amdgcn_mfma_f32_16x16x32_bf16(
                        af[ps][i], bfr[ps][j], acc[i][j], 0, 0, 0);
        }

        // WAR guard: this slot's reads complete before any wave's later
        // stage overwrites it
        asm volatile("s_waitcnt lgkmcnt(0)" ::: "memory");
        __builtin_amdgcn_s_barrier();
    }

    // tail: MFMA for kt = 15 (frag set 1)
#pragma unroll
    for (int i = 0; i < 4; ++i)
#pragma unroll
        for (int j = 0; j < 4; ++j)
            acc[i][j] = __builtin_amdgcn_mfma_f32_16x16x32_bf16(
                af[1][i], bfr[1][j], acc[i][j], 0, 0, 0);

    __syncthreads();   // full drain before ldsC aliases the ring

    // epilogue: 4 passes of 32 rows through LDS (stride 132 -> 2-way only)
    float a = stats[0];
    int row = tid >> 3, cs2 = (tid & 7) * 16;
#pragma unroll
    for (int p = 0; p < 4; ++p) {
        if (wr == (p >> 1)) {
#pragma unroll
            for (int ii = 0; ii < 2; ++ii) {
                int i = (p & 1) * 2 + ii;
                int rl0 = i * 16 + q * 4 - (p & 1) * 32;
#pragma unroll
                for (int j = 0; j < 4; ++j) {
                    int col = wc * 64 + j * 16 + l15;
#pragma unroll
                    for (int r = 0; r < 4; ++r)
                        ldsC[(rl0 + r) * 132 + col] = acc[i][j][r];
                }
            }
        }
        __syncthreads();
        int tg = mt * 128 + p * 32 + row;
        float dt = d[tg];
        size_t gbase = ((size_t)b * TDIM + tg) * FDIM + ft * 128 + cs2;
        const float* xr = x + gbase;
        float* orow = out + gbase;
#pragma unroll
        for (int k4 = 0; k4 < 4; ++k4) {
            float4 xv = *(const float4*)(xr + k4 * 4);
            float4 cv = *(const float4*)&ldsC[row * 132 + cs2 + k4 * 4];
            float4 o;
            o.x = xv.x + fmaxf(a * cv.x + dt, 0.f);
            o.y = xv.y + fmaxf(a * cv.y + dt, 0.f);
            o.z = xv.z + fmaxf(a * cv.z + dt, 0.f);
            o.w = xv.w + fmaxf(a * cv.w + dt, 0.f);
            *(float4*)(orow + k4 * 4) = o;
        }
        __syncthreads();
    }
}

// ---------------------------------------------------------------------------
extern "C" void kernel_launch(void* const* d_in, const int* in_sizes, int n_in,
                              void* d_out, int out_size, void* d_ws, size_t ws_size,
                              hipStream_t stream) {
    const float* x     = (const float*)d_in[0];
    const float* W     = (const float*)d_in[1];
    const float* bias  = (const float*)d_in[2];
    const float* gamma = (const float*)d_in[3];
    const float* beta  = (const float*)d_in[4];
    float* out = (float*)d_out;

    char* ws = (char*)d_ws;
    float*    stats    = (float*)ws;                   // 8 B
    float*    dvec     = (float*)(ws + 1024);          // 2 KB
    float*    rowsumW  = (float*)(ws + 4096);          // 2 KB
    float2*   partials = (float2*)(ws + 8192);         // 32 KB
    ushort_t* WbC      = (ushort_t*)(ws + (64 << 10)); // 512 KB
    ushort_t* xTC      = (ushort_t*)(ws + (1 << 20));  // 64 MB

    k_statsT<<<4608, 256, 0, stream>>>(x, W, xTC, WbC, rowsumW, partials);
    k_reduce<<<1, 256, 0, stream>>>(partials, rowsumW, bias, gamma, beta, stats, dvec);
    k_gemm<<<2048, 256, 0, stream>>>(WbC, xTC, x, dvec, stats, out);
}